// Round 1
// baseline (2360.802 us; speedup 1.0000x reference)
//
#include <hip/hip_runtime.h>
#include <math.h>

static constexpr int B_ = 64, L_ = 1024, D_ = 128, K_ = 256;
static constexpr long BLD_ = (long)B_ * L_ * D_;   // 8,388,608

#define TILE 64
#define KCH 16

// EPI: 0 = store acc
//      1 = store tanh(acc*scale)
//      2 = store relu(acc + C_old)
//      3 = store acc + E[b,m,n]          (residual)
//      4 = bias + pairwise-pool + global sumsq (K1)
template<int TA, int TB, int EPI>
__global__ __launch_bounds__(256)
void gemm_k(const float* __restrict__ A, long sA, int lda,
            const float* __restrict__ Bm, long sB, int ldb,
            float* __restrict__ C, long sC, int ldc,
            const float* __restrict__ E, long sE, int ldE,
            float* __restrict__ ssptr,
            int M, int N, int Kd, float scale)
{
    const int b = blockIdx.z;
    A += (long)b * sA;
    Bm += (long)b * sB;
    C += (long)b * sC;
    if (E) E += (long)b * sE;

    const int m0 = blockIdx.x * TILE;
    const int n0 = blockIdx.y * TILE;
    const int tid = threadIdx.x;
    const int tm = tid >> 4;   // 0..15
    const int tn = tid & 15;   // 0..15

    __shared__ float As[KCH][TILE + 1];
    __shared__ float Bs[KCH][TILE + 1];

    float acc[4][4] = {{0.f}};

    for (int k0 = 0; k0 < Kd; k0 += KCH) {
        if (TA == 0) {
            // A is M x K (lda = row stride): coalesce over k
            int kk = tid & 15, mm = tid >> 4;
            #pragma unroll
            for (int p = 0; p < 4; ++p)
                As[kk][mm + 16 * p] = A[(long)(m0 + mm + 16 * p) * lda + (k0 + kk)];
        } else {
            // A is K x M: coalesce over m
            int mm = tid & 63, kk = tid >> 6;
            #pragma unroll
            for (int p = 0; p < 4; ++p)
                As[kk + 4 * p][mm] = A[(long)(k0 + kk + 4 * p) * lda + (m0 + mm)];
        }
        if (TB == 0) {
            // B is K x N: coalesce over n
            int nn = tid & 63, kk = tid >> 6;
            #pragma unroll
            for (int p = 0; p < 4; ++p)
                Bs[kk + 4 * p][nn] = Bm[(long)(k0 + kk + 4 * p) * ldb + (n0 + nn)];
        } else {
            // B is N x K: coalesce over k
            int kk = tid & 15, nn = tid >> 4;
            #pragma unroll
            for (int p = 0; p < 4; ++p)
                Bs[kk][nn + 16 * p] = Bm[(long)(n0 + nn + 16 * p) * ldb + (k0 + kk)];
        }
        __syncthreads();
        #pragma unroll
        for (int kk = 0; kk < KCH; ++kk) {
            float a[4], bb[4];
            #pragma unroll
            for (int i = 0; i < 4; ++i) a[i] = As[kk][tm * 4 + i];
            #pragma unroll
            for (int j = 0; j < 4; ++j) bb[j] = Bs[kk][tn * 4 + j];
            #pragma unroll
            for (int i = 0; i < 4; ++i)
                #pragma unroll
                for (int j = 0; j < 4; ++j)
                    acc[i][j] = fmaf(a[i], bb[j], acc[i][j]);
        }
        __syncthreads();
    }

    const int mo = m0 + tm * 4;
    const int no = n0 + tn * 4;

    if (EPI == 4) {
        // v = acc + bias[n]; pooled out[m][n/2] = v[2j]+v[2j+1]; sumsq of v
        float lss = 0.f;
        #pragma unroll
        for (int i = 0; i < 4; ++i) {
            float v[4];
            #pragma unroll
            for (int j = 0; j < 4; ++j) {
                v[j] = acc[i][j] + E[no + j];
                lss += v[j] * v[j];
            }
            C[(long)(mo + i) * ldc + (no >> 1) + 0] = v[0] + v[1];
            C[(long)(mo + i) * ldc + (no >> 1) + 1] = v[2] + v[3];
        }
        __shared__ float red[256];
        red[tid] = lss;
        __syncthreads();
        #pragma unroll
        for (int s = 128; s > 0; s >>= 1) {
            if (tid < s) red[tid] += red[tid + s];
            __syncthreads();
        }
        if (tid == 0) atomicAdd(ssptr, red[0]);
    } else {
        #pragma unroll
        for (int i = 0; i < 4; ++i) {
            #pragma unroll
            for (int j = 0; j < 4; ++j) {
                long ci = (long)(mo + i) * ldc + (no + j);
                float v = acc[i][j];
                if (EPI == 1)      v = tanhf(v * scale);
                else if (EPI == 2) v = fmaxf(v + C[ci], 0.f);
                else if (EPI == 3) v = v + E[(long)(mo + i) * ldE + (no + j)];
                C[ci] = v;
            }
        }
    }
}

// z = alpha*q1 + beta*q2 (in place over q1) + per-(b,d) column sum of squares
__global__ __launch_bounds__(256)
void k2_zcolss(float* __restrict__ q1, const float* __restrict__ q2,
               const float* __restrict__ ss, float* __restrict__ colss)
{
    int b = blockIdx.x, lc = blockIdx.y;
    float n1 = sqrtf(ss[0]), n2 = sqrtf(ss[1]);
    float al = n1 / (n1 + n2), be = n2 / (n1 + n2);
    int d = threadIdx.x & 127;
    int ls = threadIdx.x >> 7;
    long base = ((long)b * L_ + (long)lc * 64) * D_;
    float acc = 0.f;
    for (int l = ls; l < 64; l += 2) {
        long idx = base + (long)l * D_ + d;
        float zv = al * q1[idx] + be * q2[idx];
        q1[idx] = zv;
        acc += zv * zv;
    }
    __shared__ float red[256];
    red[threadIdx.x] = acc;
    __syncthreads();
    if (threadIdx.x < 128)
        atomicAdd(&colss[b * D_ + d], red[threadIdx.x] + red[threadIdx.x + 128]);
}

// G = z / max(sqrt(colss[b,d]), 1e-12) in place
__global__ __launch_bounds__(256)
void k3_norm(float* __restrict__ z, const float* __restrict__ colss)
{
    long i = (long)blockIdx.x * 256 + threadIdx.x;
    int d = (int)(i & (long)(D_ - 1));
    long bl = i >> 7;           // / D_
    int b = (int)(bl >> 10);    // / L_
    float den = fmaxf(sqrtf(colss[b * D_ + d]), 1e-12f);
    z[i] = z[i] / den;
}

extern "C" void kernel_launch(void* const* d_in, const int* in_sizes, int n_in,
                              void* d_out, int out_size, void* d_ws, size_t ws_size,
                              hipStream_t stream)
{
    const float* txt = (const float*)d_in[0];
    const float* aud = (const float*)d_in[1];
    const float* vis = (const float*)d_in[2];
    const float* Wi  = (const float*)d_in[3];
    const float* bi  = (const float*)d_in[4];
    const float* Wq  = (const float*)d_in[5];
    const float* bq  = (const float*)d_in[6];
    const float* Waff[3] = { (const float*)d_in[7], (const float*)d_in[8], (const float*)d_in[9] };
    const float* Wlin[3] = { (const float*)d_in[10], (const float*)d_in[11], (const float*)d_in[12] };
    const float* Wc[3]   = { (const float*)d_in[13], (const float*)d_in[14], (const float*)d_in[15] };
    const float* Wh[3]   = { (const float*)d_in[16], (const float*)d_in[17], (const float*)d_in[18] };

    float* out = (float*)d_out;
    float* w  = (float*)d_ws;
    float* q1 = w;                         // 8,388,608 floats -> z -> G
    float* q2 = w + BLD_;                  // 8,388,608 floats -> S (per-branch)
    float* Cm = w + 2 * BLD_;              // 2,097,152 floats (B x D x 2D)
    float* Hb = Cm + 2097152;              // 2,097,152 floats (B x D x K)
    float* ss = Hb + 2097152;              // ss[0]=sum f1^2, ss[1]=sum f2^2
    float* colss = ss + 2;                 // B*D = 8192

    // zero the atomic accumulators
    hipMemsetAsync(ss, 0, (2 + B_ * D_) * sizeof(float), stream);

    // ---- BiAMLP ----
    // q1 = pool(txt@Wi + bi), ss[0] += sum f1^2 ; q2 = pool(aud@Wq + bq), ss[1]
    {
        dim3 g(B_ * L_ / TILE, 2 * D_ / TILE, 1);
        gemm_k<0,0,4><<<g, 256, 0, stream>>>(txt, 0, D_, Wi, 0, 2 * D_,
                                             q1, 0, D_, bi, 0, 0, ss + 0,
                                             B_ * L_, 2 * D_, D_, 1.f);
        gemm_k<0,0,4><<<g, 256, 0, stream>>>(aud, 0, D_, Wq, 0, 2 * D_,
                                             q2, 0, D_, bq, 0, 0, ss + 1,
                                             B_ * L_, 2 * D_, D_, 1.f);
    }
    // z = a*q1 + b*q2 in place; colss[b,d] = sum_l z^2
    k2_zcolss<<<dim3(B_, 16), 256, 0, stream>>>(q1, q2, ss, colss);
    // G = z / denom in place
    k3_norm<<<(unsigned)(BLD_ / 256), 256, 0, stream>>>(q1, colss);

    const float* G = q1;
    const float* feats_arr[3]  = { aud, vis, txt };   // branch feats
    const float* feats2_arr[3] = { aud, aud, txt };   // left half of G_src (vis uses G_ag: bug preserved)
    long outoff[3] = { BLD_, 2 * BLD_, 0 };           // return order: (txt, aud, vis)

    const long sF = (long)L_ * D_;     // per-batch stride of [B,L,D]
    const long sC2 = (long)D_ * 2 * D_;
    const long sH = (long)D_ * K_;

    for (int br = 0; br < 3; ++br) {
        const float* F  = feats_arr[br];
        const float* F2 = feats2_arr[br];
        const float* WA = Waff[br];
        const float* WL = Wlin[br];
        const float* WC = Wc[br];
        const float* WH = Wh[br];
        float* S = q2;

        // S[b,l,d] = sum_m WA[l,m] * F[b,m,d]
        gemm_k<0,0,0><<<dim3(L_ / TILE, D_ / TILE, B_), 256, 0, stream>>>(
            WA, 0, L_, F, sF, D_, S, sF, D_,
            nullptr, 0, 0, nullptr, L_, D_, L_, 1.f);

        // att left: Cm[b,d,c<128] = tanh( sum_l S[b,l,d]*F2[b,l,c] / 16 )
        gemm_k<1,0,1><<<dim3(D_ / TILE, D_ / TILE, B_), 256, 0, stream>>>(
            S, sF, D_, F2, sF, D_, Cm, sC2, 2 * D_,
            nullptr, 0, 0, nullptr, D_, D_, L_, 1.f / 16.f);

        // att right: Cm[b,d,128+c] = tanh( sum_l S[b,l,d]*G[b,l,c] / 16 )
        gemm_k<1,0,1><<<dim3(D_ / TILE, D_ / TILE, B_), 256, 0, stream>>>(
            S, sF, D_, G, sF, D_, Cm + D_, sC2, 2 * D_,
            nullptr, 0, 0, nullptr, D_, D_, L_, 1.f / 16.f);

        // U: Hb[b,d,k] = sum_l F[b,l,d]*WL[l,k]
        gemm_k<1,0,0><<<dim3(D_ / TILE, K_ / TILE, B_), 256, 0, stream>>>(
            F, sF, D_, WL, 0, K_, Hb, sH, K_,
            nullptr, 0, 0, nullptr, D_, K_, L_, 1.f);

        // T: Hb = relu(Cm @ WC + Hb)
        gemm_k<0,0,2><<<dim3(D_ / TILE, K_ / TILE, B_), 256, 0, stream>>>(
            Cm, sC2, 2 * D_, WC, 0, K_, Hb, sH, K_,
            nullptr, 0, 0, nullptr, D_, K_, 2 * D_, 1.f);

        // out[b,l,d] = sum_k WH[k,l]*Hb[b,d,k] + F[b,l,d]
        gemm_k<1,1,3><<<dim3(L_ / TILE, D_ / TILE, B_), 256, 0, stream>>>(
            WH, 0, L_, Hb, sH, K_, out + outoff[br], sF, D_,
            F, sF, D_, nullptr, L_, D_, K_, 1.f);
    }
}

// Round 2
// 914.148 us; speedup vs baseline: 2.5825x; 2.5825x over previous
//
#include <hip/hip_runtime.h>
#include <math.h>

typedef __attribute__((ext_vector_type(8))) short bf16x8;
typedef __attribute__((ext_vector_type(4))) float f32x4;

static constexpr int B_ = 64, L_ = 1024, D_ = 128, K_ = 256;
static constexpr long BLD_ = (long)B_ * L_ * D_;      // 8,388,608
static constexpr long LD_ = (long)L_ * D_;            // 131,072

__device__ __forceinline__ unsigned short f2b(float f) {
    unsigned int u = __builtin_bit_cast(unsigned int, f);
    u = (u + 0x7fffu + ((u >> 16) & 1u)) >> 16;
    return (unsigned short)u;
}
__device__ __forceinline__ float b2f(unsigned short h) {
    unsigned int u = ((unsigned int)h) << 16;
    return __builtin_bit_cast(float, u);
}

// ---------------- fp32 -> bf16 bulk convert ----------------
__global__ __launch_bounds__(256)
void cvtk(const float* __restrict__ src, unsigned short* __restrict__ dst, long n)
{
    long i = ((long)blockIdx.x * 256 + threadIdx.x) * 4;
    long stride = (long)gridDim.x * 1024;
    for (; i < n; i += stride) {
        float4 v = *(const float4*)&src[i];
        unsigned short o0 = f2b(v.x), o1 = f2b(v.y), o2 = f2b(v.z), o3 = f2b(v.w);
        unsigned int w0 = (unsigned int)o0 | ((unsigned int)o1 << 16);
        unsigned int w1 = (unsigned int)o2 | ((unsigned int)o3 << 16);
        uint2 w; w.x = w0; w.y = w1;
        *(uint2*)&dst[i] = w;
    }
}

// ---------------- MFMA GEMM ----------------
// C[M,N] = A(M,K) * B(K,N), bf16 in, fp32 accum.
// TA=0: A global [M][K].  TA=1: A global [K][M].
// TB=0: B global [K][N].  TB=1: B global [N][K].
// EPI: 0 store bf16; 1 tanh(acc*scale)->bf16; 2 relu(acc+C_old[bf16])->bf16;
//      3 acc+E(fp32)->fp32; 4 bias(E fp32)+pairwise-pool->bf16 + global sumsq
// DUALB: blockIdx.y>=1 uses B1 (column block 128.. from second source)
template<int TA, int TB, int EPI, int DUALB>
__global__ __launch_bounds__(256)
void mgemm(const unsigned short* __restrict__ A, long sA, int lda,
           const unsigned short* __restrict__ B0, const unsigned short* __restrict__ B1,
           long sB, int ldb,
           void* __restrict__ Cv, long sC, int ldc,
           const float* __restrict__ E, long sE, int ldE,
           float* __restrict__ ssptr, int Kd, float scale)
{
    const int b = blockIdx.z;
    const long m0 = (long)blockIdx.x * 128;
    const int n0 = blockIdx.y * 128;

    const unsigned short* A_ = A + (long)b * sA;
    const unsigned short* Bp = B0;
    int nB = n0;
    if (DUALB && n0 >= 128) { Bp = B1; nB = n0 - 128; }
    Bp += (long)b * sB;
    const float* E_ = E ? (E + (long)b * sE) : nullptr;

    __shared__ __align__(16) unsigned short As[128][40];
    __shared__ __align__(16) unsigned short Bs[128][40];

    const int tid = threadIdx.x;
    const int lane = tid & 63;
    const int wv = tid >> 6;
    const int wm = wv >> 1, wn = wv & 1;
    const int fr = lane & 15;
    const int kg = lane >> 4;

    f32x4 acc[4][4];
    #pragma unroll
    for (int i = 0; i < 4; ++i)
        #pragma unroll
        for (int j = 0; j < 4; ++j)
            acc[i][j] = (f32x4){0.f, 0.f, 0.f, 0.f};

    for (int k0 = 0; k0 < Kd; k0 += 32) {
        // ---- stage A ----
        if (TA == 0) {
            int row = tid >> 1, kb = (tid & 1) << 4;
            const unsigned short* src = &A_[(m0 + row) * (long)lda + k0 + kb];
            *(uint4*)&As[row][kb]     = *(const uint4*)src;
            *(uint4*)&As[row][kb + 8] = *(const uint4*)(src + 8);
        } else {
            #pragma unroll
            for (int p = 0; p < 2; ++p) {
                int k2 = (((tid >> 5) & 7) + p * 8) << 1;
                int mm = (tid & 31) << 2;
                const unsigned short* s0 = &A_[(long)(k0 + k2) * lda + m0 + mm];
                uint2 u0 = *(const uint2*)s0;
                uint2 u1 = *(const uint2*)(s0 + lda);
                const unsigned short* e0 = (const unsigned short*)&u0;
                const unsigned short* e1 = (const unsigned short*)&u1;
                #pragma unroll
                for (int i = 0; i < 4; ++i) {
                    unsigned int w = (unsigned int)e0[i] | ((unsigned int)e1[i] << 16);
                    *(unsigned int*)&As[mm + i][k2] = w;
                }
            }
        }
        // ---- stage B ----
        if (TB == 1) {
            int row = tid >> 1, kb = (tid & 1) << 4;
            const unsigned short* src = &Bp[(long)(nB + row) * ldb + k0 + kb];
            *(uint4*)&Bs[row][kb]     = *(const uint4*)src;
            *(uint4*)&Bs[row][kb + 8] = *(const uint4*)(src + 8);
        } else {
            #pragma unroll
            for (int p = 0; p < 2; ++p) {
                int k2 = (((tid >> 5) & 7) + p * 8) << 1;
                int nn = (tid & 31) << 2;
                const unsigned short* s0 = &Bp[(long)(k0 + k2) * ldb + nB + nn];
                uint2 u0 = *(const uint2*)s0;
                uint2 u1 = *(const uint2*)(s0 + ldb);
                const unsigned short* e0 = (const unsigned short*)&u0;
                const unsigned short* e1 = (const unsigned short*)&u1;
                #pragma unroll
                for (int i = 0; i < 4; ++i) {
                    unsigned int w = (unsigned int)e0[i] | ((unsigned int)e1[i] << 16);
                    *(unsigned int*)&Bs[nn + i][k2] = w;
                }
            }
        }
        __syncthreads();

        bf16x8 af[4], bfr[4];
        #pragma unroll
        for (int i = 0; i < 4; ++i)
            af[i] = *(const bf16x8*)&As[wm * 64 + i * 16 + fr][kg * 8];
        #pragma unroll
        for (int j = 0; j < 4; ++j)
            bfr[j] = *(const bf16x8*)&Bs[wn * 64 + j * 16 + fr][kg * 8];
        #pragma unroll
        for (int i = 0; i < 4; ++i)
            #pragma unroll
            for (int j = 0; j < 4; ++j)
                acc[i][j] = __builtin_amdgcn_mfma_f32_16x16x32_bf16(af[i], bfr[j], acc[i][j], 0, 0, 0);
        __syncthreads();
    }

    // ---- epilogue ----
    if (EPI == 4) {
        unsigned short* C = (unsigned short*)Cv;   // pooled bf16 [M][N/2]
        float lss = 0.f;
        #pragma unroll
        for (int i = 0; i < 4; ++i) {
            #pragma unroll
            for (int j = 0; j < 4; ++j) {
                int cg = n0 + wn * 64 + j * 16 + fr;
                float bias = E_[cg];
                f32x4 a = acc[i][j];
                #pragma unroll
                for (int r = 0; r < 4; ++r) {
                    float v = a[r] + bias;
                    lss += v * v;
                    float vp = v + __shfl_xor(v, 1);
                    if (!(fr & 1)) {
                        long row = m0 + wm * 64 + i * 16 + kg * 4 + r;
                        C[row * (long)ldc + (cg >> 1)] = f2b(vp);
                    }
                }
            }
        }
        #pragma unroll
        for (int o = 32; o; o >>= 1) lss += __shfl_xor(lss, o);
        if (lane == 0) atomicAdd(ssptr, lss);
    } else {
        #pragma unroll
        for (int i = 0; i < 4; ++i) {
            long rowb = m0 + wm * 64 + i * 16 + kg * 4;
            #pragma unroll
            for (int j = 0; j < 4; ++j) {
                int cg = n0 + wn * 64 + j * 16 + fr;
                #pragma unroll
                for (int r = 0; r < 4; ++r) {
                    long ro = rowb + r;
                    float v = acc[i][j][r];
                    if (EPI == 0) {
                        unsigned short* C = (unsigned short*)Cv + (long)b * sC;
                        C[ro * (long)ldc + cg] = f2b(v);
                    } else if (EPI == 1) {
                        unsigned short* C = (unsigned short*)Cv + (long)b * sC;
                        C[ro * (long)ldc + cg] = f2b(tanhf(v * scale));
                    } else if (EPI == 2) {
                        unsigned short* C = (unsigned short*)Cv + (long)b * sC;
                        long ci = ro * (long)ldc + cg;
                        C[ci] = f2b(fmaxf(v + b2f(C[ci]), 0.f));
                    } else if (EPI == 3) {
                        float* C = (float*)Cv + (long)b * sC;
                        C[ro * (long)ldc + cg] = v + E_[ro * (long)ldE + cg];
                    }
                }
            }
        }
    }
}

// z = al*q1 + be*q2 (bf16 in place on q1) + per-(b,d) column sumsq
__global__ __launch_bounds__(256)
void k2z(unsigned short* __restrict__ q1, const unsigned short* __restrict__ q2,
         const float* __restrict__ ss, float* __restrict__ colss)
{
    int b = blockIdx.x, lc = blockIdx.y;
    float n1 = sqrtf(ss[0]), n2 = sqrtf(ss[1]);
    float al = n1 / (n1 + n2), be = n2 / (n1 + n2);
    int d = threadIdx.x & 127, ls = threadIdx.x >> 7;
    long base = ((long)b * L_ + (long)lc * 64) * D_;
    float acc = 0.f;
    for (int l = ls; l < 64; l += 2) {
        long idx = base + (long)l * D_ + d;
        float zv = al * b2f(q1[idx]) + be * b2f(q2[idx]);
        q1[idx] = f2b(zv);
        acc += zv * zv;
    }
    __shared__ float red[256];
    red[threadIdx.x] = acc;
    __syncthreads();
    if (threadIdx.x < 128)
        atomicAdd(&colss[b * D_ + d], red[threadIdx.x] + red[threadIdx.x + 128]);
}

__global__ __launch_bounds__(256)
void k3n(unsigned short* __restrict__ z, const float* __restrict__ colss)
{
    long i = (long)blockIdx.x * 256 + threadIdx.x;
    int d = (int)(i & 127);
    int b = (int)(i >> 17);            // / (L*D) = 131072
    float den = fmaxf(sqrtf(colss[b * D_ + d]), 1e-12f);
    z[i] = f2b(b2f(z[i]) / den);
}

extern "C" void kernel_launch(void* const* d_in, const int* in_sizes, int n_in,
                              void* d_out, int out_size, void* d_ws, size_t ws_size,
                              hipStream_t stream)
{
    const float* txt = (const float*)d_in[0];
    const float* aud = (const float*)d_in[1];
    const float* vis = (const float*)d_in[2];
    const float* Wi  = (const float*)d_in[3];
    const float* bi  = (const float*)d_in[4];
    const float* Wq  = (const float*)d_in[5];
    const float* bq  = (const float*)d_in[6];
    const float* Waff[3] = { (const float*)d_in[7], (const float*)d_in[8], (const float*)d_in[9] };
    const float* Wlin[3] = { (const float*)d_in[10], (const float*)d_in[11], (const float*)d_in[12] };
    const float* Wc[3]   = { (const float*)d_in[13], (const float*)d_in[14], (const float*)d_in[15] };
    const float* Wh[3]   = { (const float*)d_in[16], (const float*)d_in[17], (const float*)d_in[18] };

    float* out = (float*)d_out;

    // ---- workspace layout (bf16 elems) ----
    unsigned short* w16 = (unsigned short*)d_ws;
    unsigned short* q1b  = w16;                 // BLD  (z -> G)
    unsigned short* q2b  = q1b + BLD_;          // BLD
    unsigned short* Sb   = q2b + BLD_;          // BLD
    unsigned short* txtb = Sb + BLD_;           // BLD
    unsigned short* audb = txtb + BLD_;         // BLD
    unsigned short* visb = audb + BLD_;         // BLD
    unsigned short* Cmb  = visb + BLD_;         // B*D*2D = 2,097,152
    unsigned short* Hbb  = Cmb + 2097152;       // B*D*K  = 2,097,152
    unsigned short* WAb  = Hbb + 2097152;       // 3 x 1,048,576
    unsigned short* WLb  = WAb + 3 * 1048576;   // 3 x 262,144
    unsigned short* WCb  = WLb + 3 * 262144;    // 3 x 65,536
    unsigned short* WHb  = WCb + 3 * 65536;     // 3 x 262,144
    unsigned short* Wib  = WHb + 3 * 262144;    // 32,768
    unsigned short* Wqb  = Wib + 32768;         // 32,768
    float* ss    = (float*)(Wqb + 32768);       // 2
    float* colss = ss + 2;                      // B*D = 8192

    hipMemsetAsync(ss, 0, (2 + B_ * D_) * sizeof(float), stream);

    auto cvt = [&](const float* s, unsigned short* d, long n) {
        long g = (n + 1023) / 1024; if (g > 2048) g = 2048;
        cvtk<<<(unsigned)g, 256, 0, stream>>>(s, d, n);
    };
    cvt(txt, txtb, BLD_);
    cvt(aud, audb, BLD_);
    cvt(vis, visb, BLD_);
    for (int i = 0; i < 3; ++i) {
        cvt(Waff[i], WAb + (long)i * 1048576, 1048576);
        cvt(Wlin[i], WLb + (long)i * 262144, 262144);
        cvt(Wc[i],   WCb + (long)i * 65536, 65536);
        cvt(Wh[i],   WHb + (long)i * 262144, 262144);
    }
    cvt(Wi, Wib, 32768);
    cvt(Wq, Wqb, 32768);

    // ---- BiAMLP: q1 = pool(txt@Wi+bi), ss[0]; q2 = pool(aud@Wq+bq), ss[1]
    mgemm<0,0,4,0><<<dim3(B_ * L_ / 128, 2, 1), 256, 0, stream>>>(
        txtb, 0, D_, Wib, nullptr, 0, 2 * D_,
        q1b, 0, D_, bi, 0, 0, ss + 0, D_, 1.f);
    mgemm<0,0,4,0><<<dim3(B_ * L_ / 128, 2, 1), 256, 0, stream>>>(
        audb, 0, D_, Wqb, nullptr, 0, 2 * D_,
        q2b, 0, D_, bq, 0, 0, ss + 1, D_, 1.f);

    k2z<<<dim3(B_, 16), 256, 0, stream>>>(q1b, q2b, ss, colss);
    k3n<<<(unsigned)(BLD_ / 256), 256, 0, stream>>>(q1b, colss);

    const unsigned short* Gb = q1b;
    const unsigned short* featsb[3]  = { audb, visb, txtb };
    const unsigned short* feats2b[3] = { audb, audb, txtb };
    const float* featsf[3] = { aud, vis, txt };
    long outoff[3] = { BLD_, 2 * BLD_, 0 };   // return order (txt, aud, vis)
    const long sC2 = (long)D_ * 2 * D_;       // 32768
    const long sH  = (long)D_ * K_;           // 32768

    for (int br = 0; br < 3; ++br) {
        const unsigned short* Fb  = featsb[br];
        const unsigned short* F2b = feats2b[br];
        const unsigned short* WAp = WAb + (long)br * 1048576;
        const unsigned short* WLp = WLb + (long)br * 262144;
        const unsigned short* WCp = WCb + (long)br * 65536;
        const unsigned short* WHp = WHb + (long)br * 262144;

        // S[b,l,d] = sum_m WA[l,m] * F[b,m,d]
        mgemm<0,0,0,0><<<dim3(L_ / 128, 1, B_), 256, 0, stream>>>(
            WAp, 0, L_, Fb, nullptr, LD_, D_,
            Sb, LD_, D_, nullptr, 0, 0, nullptr, L_, 1.f);

        // att: Cm[b,d,c] = tanh( sum_l S[b,l,d]*Bsel[b,l,c] / 16 ), Bsel = F2 | G
        mgemm<1,0,1,1><<<dim3(1, 2, B_), 256, 0, stream>>>(
            Sb, LD_, D_, F2b, Gb, LD_, D_,
            Cmb, sC2, 2 * D_, nullptr, 0, 0, nullptr, L_, 1.f / 16.f);

        // U: Hb[b,d,k] = sum_l F[b,l,d]*WL[l,k]
        mgemm<1,0,0,0><<<dim3(1, 2, B_), 256, 0, stream>>>(
            Fb, LD_, D_, WLp, nullptr, 0, K_,
            Hbb, sH, K_, nullptr, 0, 0, nullptr, L_, 1.f);

        // T: Hb = relu(Cm @ WC + Hb)
        mgemm<0,0,2,0><<<dim3(1, 2, B_), 256, 0, stream>>>(
            Cmb, sC2, 2 * D_, WCp, nullptr, 0, K_,
            Hbb, sH, K_, nullptr, 0, 0, nullptr, 2 * D_, 1.f);

        // out[b,l,d] = sum_k WH[k,l]*Hb[b,d,k] + F[b,l,d]
        mgemm<1,1,3,0><<<dim3(L_ / 128, 1, B_), 256, 0, stream>>>(
            WHp, 0, L_, Hbb, nullptr, sH, K_,
            out + outoff[br], LD_, D_, featsf[br], LD_, D_, nullptr, K_, 1.f);
    }
}

// Round 4
// 416.919 us; speedup vs baseline: 5.6625x; 2.1926x over previous
//
#include <hip/hip_runtime.h>
#include <math.h>

typedef __attribute__((ext_vector_type(8))) short bf16x8;
typedef __attribute__((ext_vector_type(4))) float f32x4;

static constexpr int B_ = 64, L_ = 1024, D_ = 128, K_ = 256;
static constexpr long BLD_ = (long)B_ * L_ * D_;      // 8,388,608
static constexpr long LD_  = (long)L_ * D_;           // 131,072

__device__ __forceinline__ unsigned short f2b(float f) {
    unsigned int u = __builtin_bit_cast(unsigned int, f);
    u = (u + 0x7fffu + ((u >> 16) & 1u)) >> 16;
    return (unsigned short)u;
}
__device__ __forceinline__ float b2f(unsigned short h) {
    unsigned int u = ((unsigned int)h) << 16;
    return __builtin_bit_cast(float, u);
}

__device__ __forceinline__ void gl16(const unsigned short* g, unsigned short* s) {
    __builtin_amdgcn_global_load_lds(
        (const __attribute__((address_space(1))) unsigned int*)g,
        (__attribute__((address_space(3))) unsigned int*)s, 16, 0, 0);
}

// ---------------- fused transpose+convert: fp32 [R][C] -> bf16 [C][R] ----------------
struct TrEnt { const float* src; unsigned short* dst; int R, C, nb, start; };
struct TrTab { TrEnt e[14]; };

__global__ __launch_bounds__(256)
void trk(TrTab tab)
{
    __shared__ unsigned short T[64][72];
    int bid = blockIdx.x;
    int ei = 0;
    #pragma unroll
    for (int i = 1; i < 14; ++i) if (bid >= tab.e[i].start) ei = i;
    TrEnt e = tab.e[ei];
    int tile = bid - e.start;
    int ntR = e.R >> 6, ntC = e.C >> 6;
    int nt = ntR * ntC;
    int bb = tile / nt, tt = tile - bb * nt;
    int ri = tt % ntR, ci = tt / ntR;
    const float* src = e.src + (long)bb * e.R * e.C + (long)(ri * 64) * e.C + ci * 64;
    unsigned short* dst = e.dst + (long)bb * e.R * e.C + (long)(ci * 64) * e.R + ri * 64;
    int t = threadIdx.x;
    {
        int r = t >> 2, cq = t & 3;
        const float* s = src + (long)r * e.C + cq * 16;
        unsigned short tmp[16];
        #pragma unroll
        for (int f = 0; f < 4; ++f) {
            float4 v = *(const float4*)(s + f * 4);
            tmp[f*4+0]=f2b(v.x); tmp[f*4+1]=f2b(v.y); tmp[f*4+2]=f2b(v.z); tmp[f*4+3]=f2b(v.w);
        }
        *(uint4*)&T[r][cq*16]   = *(uint4*)&tmp[0];
        *(uint4*)&T[r][cq*16+8] = *(uint4*)&tmp[8];
    }
    __syncthreads();
    {
        int cr = t >> 2, rq = t & 3;
        unsigned short tmp[16];
        #pragma unroll
        for (int j = 0; j < 16; ++j) tmp[j] = T[rq*16 + j][cr];
        unsigned short* dp = dst + (long)cr * e.R + rq * 16;
        *(uint4*)&dp[0] = *(uint4*)&tmp[0];
        *(uint4*)&dp[8] = *(uint4*)&tmp[8];
    }
}

// plain fp32->bf16 convert for the three WA matrices (no transpose)
__global__ __launch_bounds__(256)
void cvt3(const float* s0, const float* s1, const float* s2,
          unsigned short* d, long n)
{
    const float* s = blockIdx.y == 0 ? s0 : blockIdx.y == 1 ? s1 : s2;
    unsigned short* dd = d + (long)blockIdx.y * n;
    long i = ((long)blockIdx.x * 256 + threadIdx.x) * 4;
    long stride = (long)gridDim.x * 1024;
    for (; i < n; i += stride) {
        float4 v = *(const float4*)&s[i];
        unsigned int w0 = (unsigned int)f2b(v.x) | ((unsigned int)f2b(v.y) << 16);
        unsigned int w1 = (unsigned int)f2b(v.z) | ((unsigned int)f2b(v.w) << 16);
        uint2 w; w.x = w0; w.y = w1;
        *(uint2*)&dd[i] = w;
    }
}

// ---------------- unified MFMA GEMM ----------------
struct OpDesc {
    const unsigned short* A;
    long aOff0, aOff1, aOff2, sA;
    int lda;
    const unsigned short* B0;
    long bOff0, bOff1, bOff2, sB0;
    const unsigned short* B1;
    long sB1;
    int ldb;
    void* C;
    long sC;
    int ldc;
    const float* E0; const float* E1; const float* E2;
    float* ss;
    int Kd;
};

// EPI: 0 store bf16; 1 tanh(acc/16)->bf16; 2 relu(acc+C_old)->bf16 inplace;
//      3 fp32 out + residual (branch-ordered); 4 bias+pool->bf16 + global sumsq
template<int EPI, int AF32>
__device__ __forceinline__ void gbody(const OpDesc& d, int zrem,
                                      unsigned short (*As)[128][32],
                                      unsigned short (*Bs)[128][32])
{
    const int tid = threadIdx.x;
    const long m0 = (long)blockIdx.x * 128;
    const int n0 = blockIdx.y * 128;
    const int br = zrem >> 6, bb = zrem & 63;

    long aO = (br == 0 ? d.aOff0 : br == 1 ? d.aOff1 : d.aOff2) + (long)bb * d.sA;
    const unsigned short* A_ = d.A + aO;
    const float* Af = (const float*)d.A;
    const unsigned short* Bp;
    int nB = n0;
    if (d.B1 && n0 >= 128) { Bp = d.B1 + (long)bb * d.sB1; nB = n0 - 128; }
    else { Bp = d.B0 + (br == 0 ? d.bOff0 : br == 1 ? d.bOff1 : d.bOff2) + (long)bb * d.sB0; }

    const int w = tid >> 6, l = tid & 63;
    const int wm = w >> 1, wn = w & 1;
    const int fr = l & 15, kg = l >> 4;

    f32x4 acc[4][4];
    #pragma unroll
    for (int i = 0; i < 4; ++i)
        #pragma unroll
        for (int j = 0; j < 4; ++j)
            acc[i][j] = (f32x4){0.f, 0.f, 0.f, 0.f};

    auto stage = [&](int buf, int k0) {
        if (AF32) {
            int row = tid >> 1, half = tid & 1;
            const float* s = Af + (long)(m0 + row) * d.lda + k0 + half * 16;
            unsigned short tmp[16];
            #pragma unroll
            for (int f = 0; f < 4; ++f) {
                float4 v = *(const float4*)(s + f * 4);
                tmp[f*4+0]=f2b(v.x); tmp[f*4+1]=f2b(v.y); tmp[f*4+2]=f2b(v.z); tmp[f*4+3]=f2b(v.w);
            }
            *(uint4*)&As[buf][row][half*16]     = *(uint4*)&tmp[0];
            *(uint4*)&As[buf][row][half*16 + 8] = *(uint4*)&tmp[8];
        } else {
            const unsigned short* ga = A_ + (m0 + 32*w + (l >> 2)) * (long)d.lda + k0 + (l & 3) * 8;
            gl16(ga,                    &As[buf][32*w][0]);
            gl16(ga + 16*(long)d.lda,   &As[buf][32*w + 16][0]);
        }
        const unsigned short* gb = Bp + (long)(nB + 32*w + (l >> 2)) * d.ldb + k0 + (l & 3) * 8;
        gl16(gb,                  &Bs[buf][32*w][0]);
        gl16(gb + 16*(long)d.ldb, &Bs[buf][32*w + 16][0]);
    };

    const int nt = d.Kd >> 5;
    stage(0, 0);
    __syncthreads();
    for (int t = 0; t < nt; ++t) {
        if (t + 1 < nt) stage((t + 1) & 1, (t + 1) << 5);
        const int cb = t & 1;
        bf16x8 af[4], bf[4];
        #pragma unroll
        for (int i = 0; i < 4; ++i) af[i] = *(const bf16x8*)&As[cb][wm*64 + i*16 + fr][kg*8];
        #pragma unroll
        for (int j = 0; j < 4; ++j) bf[j] = *(const bf16x8*)&Bs[cb][wn*64 + j*16 + fr][kg*8];
        #pragma unroll
        for (int i = 0; i < 4; ++i)
            #pragma unroll
            for (int j = 0; j < 4; ++j)
                acc[i][j] = __builtin_amdgcn_mfma_f32_16x16x32_bf16(af[i], bf[j], acc[i][j], 0, 0, 0);
        __syncthreads();
    }

    if (EPI == 4) {
        unsigned short* C = (unsigned short*)d.C;
        float lss = 0.f;
        #pragma unroll
        for (int i = 0; i < 4; ++i) {
            #pragma unroll
            for (int j = 0; j < 4; ++j) {
                int cg = n0 + wn*64 + j*16 + fr;
                float bias = d.E0[cg];
                #pragma unroll
                for (int r = 0; r < 4; ++r) {
                    float v = acc[i][j][r] + bias;
                    lss += v * v;
                    float vp = v + __shfl_xor(v, 1);
                    if (!(fr & 1)) {
                        long row = m0 + wm*64 + i*16 + kg*4 + r;
                        C[row * (long)d.ldc + (cg >> 1)] = f2b(vp);
                    }
                }
            }
        }
        #pragma unroll
        for (int o = 32; o; o >>= 1) lss += __shfl_xor(lss, o);
        if (l == 0) atomicAdd(d.ss, lss);
    } else if (EPI == 3) {
        long off = (br == 2) ? 0L : (long)(br + 1) * BLD_;
        float* Co = (float*)d.C + off + (long)bb * LD_;
        const float* Ep = (br == 0 ? d.E0 : br == 1 ? d.E1 : d.E2) + (long)bb * LD_;
        #pragma unroll
        for (int i = 0; i < 4; ++i) {
            long rowb = m0 + wm*64 + i*16 + kg*4;
            #pragma unroll
            for (int j = 0; j < 4; ++j) {
                int cg = n0 + wn*64 + j*16 + fr;
                #pragma unroll
                for (int r = 0; r < 4; ++r) {
                    long ci = (rowb + r) * (long)d.ldc + cg;
                    Co[ci] = acc[i][j][r] + Ep[ci];
                }
            }
        }
    } else {
        unsigned short* C = (unsigned short*)d.C + (long)zrem * d.sC;
        #pragma unroll
        for (int i = 0; i < 4; ++i) {
            long rowb = m0 + wm*64 + i*16 + kg*4;
            #pragma unroll
            for (int j = 0; j < 4; ++j) {
                int cg = n0 + wn*64 + j*16 + fr;
                #pragma unroll
                for (int r = 0; r < 4; ++r) {
                    long ci = (rowb + r) * (long)d.ldc + cg;
                    float v = acc[i][j][r];
                    if (EPI == 0)      C[ci] = f2b(v);
                    else if (EPI == 1) C[ci] = f2b(tanhf(v * 0.0625f));
                    else               C[ci] = f2b(fmaxf(v + b2f(C[ci]), 0.f));
                }
            }
        }
    }
}

template<int EPI0, int EPI1, int AF32>
__global__ __launch_bounds__(256)
void mg(OpDesc d0, OpDesc d1, int zsplit)
{
    __shared__ unsigned short As[2][128][32];
    __shared__ unsigned short Bs[2][128][32];
    int z = blockIdx.z;
    if (z < zsplit) gbody<EPI0, AF32>(d0, z, As, Bs);
    else            gbody<EPI1, AF32>(d1, z - zsplit, As, Bs);
}

// z = al*q1 + be*q2 (bf16 in place on q1) + per-(b,d) column sumsq
__global__ __launch_bounds__(256)
void k2z(unsigned short* __restrict__ q1, const unsigned short* __restrict__ q2,
         const float* __restrict__ ss, float* __restrict__ colss)
{
    int b = blockIdx.x, lc = blockIdx.y;
    float n1 = sqrtf(ss[0]), n2 = sqrtf(ss[1]);
    float al = n1 / (n1 + n2), be = n2 / (n1 + n2);
    int d = threadIdx.x & 127, ls = threadIdx.x >> 7;
    long base = ((long)b * L_ + (long)lc * 64) * D_;
    float acc = 0.f;
    for (int ll = ls; ll < 64; ll += 2) {
        long idx = base + (long)ll * D_ + d;
        float zv = al * b2f(q1[idx]) + be * b2f(q2[idx]);
        q1[idx] = f2b(zv);
        acc += zv * zv;
    }
    __shared__ float red[256];
    red[threadIdx.x] = acc;
    __syncthreads();
    if (threadIdx.x < 128)
        atomicAdd(&colss[b * D_ + d], red[threadIdx.x] + red[threadIdx.x + 128]);
}

// GT[b][d][l] = z[b][l][d] / max(sqrt(colss[b,d]),1e-12)
__global__ __launch_bounds__(256)
void k3nT(const unsigned short* __restrict__ z, const float* __restrict__ colss,
          unsigned short* __restrict__ GT)
{
    __shared__ unsigned short T[128][136];
    int b = blockIdx.x, lt = blockIdx.y;
    int t = threadIdx.x;
    {
        int r = t >> 1, half = t & 1;
        const unsigned short* src = z + ((long)b * L_ + lt * 128 + r) * D_ + half * 64;
        #pragma unroll
        for (int q = 0; q < 8; ++q)
            *(uint4*)&T[r][half*64 + q*8] = *(const uint4*)(src + q*8);
    }
    __syncthreads();
    {
        int d = t >> 1, lh = t & 1;
        float inv = 1.f / fmaxf(sqrtf(colss[b * D_ + d]), 1e-12f);
        unsigned short tmp[64];
        #pragma unroll
        for (int j = 0; j < 64; ++j) tmp[j] = f2b(b2f(T[lh*64 + j][d]) * inv);
        unsigned short* dp = GT + ((long)b * D_ + d) * L_ + lt * 128 + lh * 64;
        #pragma unroll
        for (int q = 0; q < 8; ++q) *(uint4*)&dp[q*8] = *(uint4*)&tmp[q*8];
    }
}

extern "C" void kernel_launch(void* const* d_in, const int* in_sizes, int n_in,
                              void* d_out, int out_size, void* d_ws, size_t ws_size,
                              hipStream_t stream)
{
    const float* txt = (const float*)d_in[0];
    const float* aud = (const float*)d_in[1];
    const float* vis = (const float*)d_in[2];
    const float* Wi  = (const float*)d_in[3];
    const float* bi  = (const float*)d_in[4];
    const float* Wq  = (const float*)d_in[5];
    const float* bq  = (const float*)d_in[6];
    const float* Waff[3] = { (const float*)d_in[7], (const float*)d_in[8], (const float*)d_in[9] };
    const float* Wlin[3] = { (const float*)d_in[10], (const float*)d_in[11], (const float*)d_in[12] };
    const float* Wc[3]   = { (const float*)d_in[13], (const float*)d_in[14], (const float*)d_in[15] };
    const float* Wh[3]   = { (const float*)d_in[16], (const float*)d_in[17], (const float*)d_in[18] };

    // ---- workspace (bf16 elems) ----
    unsigned short* w16 = (unsigned short*)d_ws;
    unsigned short* featT = w16;                      // 3*BLD  [aud,vis,txt] x [b][d][l]
    unsigned short* q1b   = featT + 3 * BLD_;         // 8,388,608
    unsigned short* q2b   = q1b + BLD_;               // 8,388,608
    unsigned short* WAb   = q2b + BLD_;               // 3,145,728
    unsigned short* WLTb  = WAb + 3145728;            // 786,432   [256][1024] x3
    unsigned short* WCTb  = WLTb + 786432;            // 196,608   [256][256] x3
    unsigned short* WHTb  = WCTb + 196608;            // 786,432   [1024][256] x3
    unsigned short* WiTb  = WHTb + 786432;            // 32,768    [256][128]
    unsigned short* WqTb  = WiTb + 32768;             // 32,768
    float* ssf   = (float*)(WqTb + 32768);            // 2
    float* colss = ssf + 2;                           // 8192
    // overlays (q1/q2 dead after k3nT)
    unsigned short* Cm3 = q1b;                        // 6,291,456
    unsigned short* Hb3 = q1b + 6291456;              // 6,291,456
    // d_out scratch (fully overwritten by final GEMM)
    unsigned short* S2all = (unsigned short*)d_out;   // 25,165,824
    unsigned short* GT    = S2all + 3 * BLD_;         // 8,388,608

    hipMemsetAsync(ssf, 0, (2 + B_ * D_) * sizeof(float), stream);

    // ---- transposes/conversions ----
    TrTab tab;
    auto setE = [&](int i, const float* s, unsigned short* dst, int R, int C, int nb, int start) {
        tab.e[i].src = s; tab.e[i].dst = dst; tab.e[i].R = R; tab.e[i].C = C;
        tab.e[i].nb = nb; tab.e[i].start = start;
    };
    int st = 0;
    setE(0, aud, featT + 0,        1024, 128, 64, st); st += 2048;
    setE(1, vis, featT + BLD_,     1024, 128, 64, st); st += 2048;
    setE(2, txt, featT + 2 * BLD_, 1024, 128, 64, st); st += 2048;
    setE(3, Wi, WiTb, 128, 256, 1, st); st += 8;
    setE(4, Wq, WqTb, 128, 256, 1, st); st += 8;
    for (int i = 0; i < 3; ++i) { setE(5 + i, Wlin[i], WLTb + (long)i * 262144, 1024, 256, 1, st); st += 64; }
    for (int i = 0; i < 3; ++i) { setE(8 + i, Wc[i],   WCTb + (long)i * 65536,  256, 256, 1, st); st += 16; }
    for (int i = 0; i < 3; ++i) { setE(11 + i, Wh[i],  WHTb + (long)i * 262144, 256, 1024, 1, st); st += 64; }
    trk<<<st, 256, 0, stream>>>(tab);
    cvt3<<<dim3(1024, 3), 256, 0, stream>>>(Waff[0], Waff[1], Waff[2], WAb, 1048576);

    // ---- BiAMLP (txt|aud merged) ----
    OpDesc dTxt = {}, dAud = {};
    dTxt.A = (const unsigned short*)txt; dTxt.lda = 128;
    dTxt.B0 = WiTb; dTxt.ldb = 128;
    dTxt.C = q1b; dTxt.ldc = 128;
    dTxt.E0 = bi; dTxt.ss = ssf + 0; dTxt.Kd = 128;
    dAud = dTxt;
    dAud.A = (const unsigned short*)aud; dAud.B0 = WqTb; dAud.C = q2b;
    dAud.E0 = bq; dAud.ss = ssf + 1;
    mg<4, 4, 1><<<dim3(512, 2, 2), 256, 0, stream>>>(dTxt, dAud, 1);

    k2z<<<dim3(64, 16), 256, 0, stream>>>(q1b, q2b, ssf, colss);
    k3nT<<<dim3(64, 8), 256, 0, stream>>>(q1b, colss, GT);

    // ---- S2[br][b][d][l] = featT[br][b] @ WA[br] (B natural [N=l][K=m]) ----
    OpDesc dS2 = {};
    dS2.A = featT; dS2.aOff0 = 0; dS2.aOff1 = BLD_; dS2.aOff2 = 2 * BLD_;
    dS2.sA = LD_; dS2.lda = 1024;
    dS2.B0 = WAb; dS2.bOff0 = 0; dS2.bOff1 = 1048576; dS2.bOff2 = 2097152;
    dS2.sB0 = 0; dS2.ldb = 1024;
    dS2.C = S2all; dS2.sC = LD_; dS2.ldc = 1024; dS2.Kd = 1024;
    mg<0, 0, 0><<<dim3(1, 8, 192), 256, 0, stream>>>(dS2, dS2, 192);

    // ---- att (tanh) + U merged ----
    OpDesc dAtt = {};
    dAtt.A = S2all; dAtt.aOff0 = 0; dAtt.aOff1 = 64 * LD_; dAtt.aOff2 = 128 * LD_;
    dAtt.sA = LD_; dAtt.lda = 1024;
    dAtt.B0 = featT; dAtt.bOff0 = 0; dAtt.bOff1 = 0; dAtt.bOff2 = 2 * BLD_;  // audT,audT,txtT
    dAtt.sB0 = LD_;
    dAtt.B1 = GT; dAtt.sB1 = LD_; dAtt.ldb = 1024;
    dAtt.C = Cm3; dAtt.sC = 32768; dAtt.ldc = 256; dAtt.Kd = 1024;
    OpDesc dU = {};
    dU.A = featT; dU.aOff0 = 0; dU.aOff1 = BLD_; dU.aOff2 = 2 * BLD_;
    dU.sA = LD_; dU.lda = 1024;
    dU.B0 = WLTb; dU.bOff0 = 0; dU.bOff1 = 262144; dU.bOff2 = 524288;
    dU.sB0 = 0; dU.ldb = 1024;
    dU.C = Hb3; dU.sC = 32768; dU.ldc = 256; dU.Kd = 1024;
    mg<1, 0, 0><<<dim3(1, 2, 384), 256, 0, stream>>>(dAtt, dU, 192);

    // ---- T: Hb = relu(Cm @ WC + Hb) ----
    OpDesc dT = {};
    dT.A = Cm3; dT.aOff0 = 0; dT.aOff1 = 2097152; dT.aOff2 = 4194304;
    dT.sA = 32768; dT.lda = 256;
    dT.B0 = WCTb; dT.bOff0 = 0; dT.bOff1 = 65536; dT.bOff2 = 131072;
    dT.sB0 = 0; dT.ldb = 256;
    dT.C = Hb3; dT.sC = 32768; dT.ldc = 256; dT.Kd = 256;
    mg<2, 2, 0><<<dim3(1, 2, 192), 256, 0, stream>>>(dT, dT, 192);

    // ---- out: out[b,l,d] = WH^T @ Hb^T + residual ----
    OpDesc dOut = {};
    dOut.A = WHTb; dOut.aOff0 = 0; dOut.aOff1 = 262144; dOut.aOff2 = 524288;
    dOut.sA = 0; dOut.lda = 256;
    dOut.B0 = Hb3; dOut.bOff0 = 0; dOut.bOff1 = 2097152; dOut.bOff2 = 4194304;
    dOut.sB0 = 32768; dOut.ldb = 256;
    dOut.C = d_out; dOut.ldc = 128;
    dOut.E0 = aud; dOut.E1 = vis; dOut.E2 = txt; dOut.Kd = 256;
    mg<3, 3, 0><<<dim3(8, 1, 192), 256, 0, stream>>>(dOut, dOut, 192);
}